// Round 7
// baseline (33701.138 us; speedup 1.0000x reference)
//
#include <hip/hip_runtime.h>
#include <stdint.h>

#define S_ 128
#define L_ 128
#define E_ 300
#define H_ 300
#define NMAX (S_*L_)          // 16384
#define R_ 1200               // 4*H
#define D_ 600
#define XW_STRIDE ((size_t)NMAX*R_)

// ---------------- prep: prefix sums, token->(s,l) map, zero h buffers -------
__global__ void prep_kernel(const int* __restrict__ lengths, int* __restrict__ meta,
                            int* __restrict__ map, unsigned long long* __restrict__ hbuf) {
    __shared__ int offs[S_];
    int tid = threadIdx.x;
    if (tid == 0) {
        int acc = 0;
        for (int s = 0; s < S_; s++) { offs[s] = acc; acc += lengths[s]; }
        meta[0] = acc;   // N total
    }
    __syncthreads();
    for (int s = tid; s < S_; s += blockDim.x) {
        int o = offs[s], len = lengths[s];
        for (int l = 0; l < len; l++) map[o + l] = s * L_ + l;
    }
    // zero hbuf: [2 dirs][2 slots][320] u64 (tag 0 == valid h_0 = 0)
    for (int i = tid; i < 2*2*320; i += blockDim.x) hbuf[i] = 0ull;
}

// ---------------- xw = embeds @ Wih^T + (bih+bhh), both directions ----------
__global__ __launch_bounds__(256, 1) void xw_kernel(
    const int* __restrict__ tokens, const float* __restrict__ table,
    const float* __restrict__ Wih_f, const float* __restrict__ bih_f, const float* __restrict__ bhh_f,
    const float* __restrict__ Wih_b, const float* __restrict__ bih_b, const float* __restrict__ bhh_b,
    const int* __restrict__ meta, const int* __restrict__ map, float* __restrict__ xw) {
    const int N = meta[0];
    const int n0 = blockIdx.x * 32;
    if (n0 >= N) return;
    const int r = blockIdx.y * 256 + threadIdx.x;   // 0..2559
    const bool vr = (r < 2*R_);
    const int dir = (r >= R_) ? 1 : 0;
    const int rr = r - dir * R_;
    const float* W = dir ? Wih_b : Wih_f;
    float bias = 0.f;
    float4 w4[75];
    if (vr) {
        bias = dir ? (bih_b[rr] + bhh_b[rr]) : (bih_f[rr] + bhh_f[rr]);
        #pragma unroll
        for (int j = 0; j < 75; j++) w4[j] = *(const float4*)(W + (size_t)rr * E_ + 4*j);
    } else {
        #pragma unroll
        for (int j = 0; j < 75; j++) w4[j] = make_float4(0.f, 0.f, 0.f, 0.f);
    }
    float* xwd = xw + (size_t)dir * XW_STRIDE;
    const int iend = min(32, N - n0);
    for (int i = 0; i < iend; i++) {
        const int n = n0 + i;
        const int tok = tokens[map[n]];                  // uniform
        const float* arow = table + (size_t)tok * E_;
        float a0 = bias, a1 = 0.f, a2 = 0.f, a3 = 0.f;
        #pragma unroll
        for (int j = 0; j < 75; j++) {
            float4 a4 = *(const float4*)(arow + 4*j);    // uniform -> scalar path
            a0 = fmaf(w4[j].x, a4.x, a0);
            a1 = fmaf(w4[j].y, a4.y, a1);
            a2 = fmaf(w4[j].z, a4.z, a2);
            a3 = fmaf(w4[j].w, a4.w, a3);
        }
        if (vr) xwd[(size_t)n * R_ + rr] = (a0 + a1) + (a2 + a3);
    }
}

// ---------------- sequential BiLSTM scan -------------------------------------
__device__ __forceinline__ float sel4(int m, float a, float b, float c, float d) {
    float r = a;
    r = (m == 1) ? b : r;
    r = (m == 2) ? c : r;
    r = (m == 3) ? d : r;
    return r;
}
// fast activations (v_exp_f32 + v_rcp_f32); NaN-free at +/-inf
__device__ __forceinline__ float sigm(float x) {
    return __builtin_amdgcn_rcpf(1.f + __expf(-x));
}
__device__ __forceinline__ float tanh_fast(float x) {
    return 1.f - 2.f * __builtin_amdgcn_rcpf(1.f + __expf(2.f * x));
}

// grid: 20 blocks x 256 threads. block b: dir=b/10, blk=b%10 (32 h-dims).
// thread: pair=tid>>1 owns Whh row (gate=pair&3, d=32*blk+(pair>>2));
// half=tid&1 owns half the 300-wide dot.
// RESIDENCY SIDESTEP: weights are re-loaded EVERY STEP (38 dwordx4 from L2,
// issued BEFORE the poll loop, ordered by an asm memory barrier). The poll's
// own s_waitcnt vmcnt(0) drains them -> the entire L2 weight stream hides
// under the sync wait. No resident array for the allocator to demote.
// h exchanged via tagged u64 hbuf[dir][slot][dim] at AGENT scope (tag=step).
__global__ __launch_bounds__(256, 1) void scan_kernel(
    const float* Whh_f, const float* Whh_b,
    const int* __restrict__ meta, const int* __restrict__ map,
    unsigned long long* __restrict__ hbuf, const float* __restrict__ xw,
    float* __restrict__ padded) {
    const int N = meta[0];
    const int b = blockIdx.x;
    const int dir = b / 10;
    const int blk = b % 10;
    const int tid = threadIdx.x;
    const int wave = tid >> 6;
    const int lane = tid & 63;
    const int pair = tid >> 1;            // 0..127
    const int half = tid & 1;
    const int gate = pair & 3;
    const int d = 32 * blk + (pair >> 2); // h dim this row-group computes
    const bool vd = (d < H_);
    if (32 * blk + 8 * wave >= H_) return;   // wave-uniform tail exit

    const float* Whh = dir ? Whh_b : Whh_f;
    const int row = gate * H_ + (vd ? d : 0);
    const int cbase = half ? 148 : 0;     // half0: cols 0..147, half1: 148..299
    const float* wr = Whh + (size_t)row * H_ + cbase;   // 16B-aligned both halves

    const float* xwd = xw + (size_t)dir * XW_STRIDE;
    unsigned long long* hb = hbuf + dir * 2 * 320;

    __shared__ float hl[4][304];
    float* hw = hl[wave];

    float c = 0.f;
    const bool storer = (vd && gate == 0 && half == 0);
    const int pd = dir * H_ + d;          // padded column for this row-group

    for (int t = 0; t < N; t++) {
        const int n = dir ? (N - 1 - t) : t;

        // ---- pre-poll issue region: xw, map, and the 38 weight float4s ----
        const float xw_t = xwd[(size_t)n * R_ + row];
        const int   m_t  = map[n];
        float4 w4[38];
        #pragma unroll
        for (int j = 0; j < 37; j++) w4[j] = *(const float4*)(wr + 4*j);
        w4[37] = half ? *(const float4*)(wr + 148)
                      : make_float4(0.f, 0.f, 0.f, 0.f);
        // Barrier: loads above cannot hoist out of the loop or sink below the
        // poll; their latency drains under the poll's first s_waitcnt.
        asm volatile("" ::: "memory");

        // ---- poll h_t (tag == t) ----
        const unsigned long long* hp = hb + (size_t)(t & 1) * 320;
        const unsigned int want = (unsigned int)t;
        unsigned long long v0, v1, v2, v3, v4;
        for (;;) {
            v0 = __hip_atomic_load(hp + lane,        __ATOMIC_RELAXED, __HIP_MEMORY_SCOPE_AGENT);
            v1 = __hip_atomic_load(hp + 64  + lane,  __ATOMIC_RELAXED, __HIP_MEMORY_SCOPE_AGENT);
            v2 = __hip_atomic_load(hp + 128 + lane,  __ATOMIC_RELAXED, __HIP_MEMORY_SCOPE_AGENT);
            v3 = __hip_atomic_load(hp + 192 + lane,  __ATOMIC_RELAXED, __HIP_MEMORY_SCOPE_AGENT);
            v4 = (lane < 44) ? __hip_atomic_load(hp + 256 + lane, __ATOMIC_RELAXED, __HIP_MEMORY_SCOPE_AGENT)
                             : ((unsigned long long)want << 32);
            bool ok = ((unsigned int)(v0 >> 32) == want) &&
                      ((unsigned int)(v1 >> 32) == want) &&
                      ((unsigned int)(v2 >> 32) == want) &&
                      ((unsigned int)(v3 >> 32) == want) &&
                      ((unsigned int)(v4 >> 32) == want);
            if (ok) break;
        }
        // stage h into this wave's LDS copy
        hw[lane]        = __uint_as_float((unsigned int)v0);
        hw[64  + lane]  = __uint_as_float((unsigned int)v1);
        hw[128 + lane]  = __uint_as_float((unsigned int)v2);
        hw[192 + lane]  = __uint_as_float((unsigned int)v3);
        if (lane < 44) hw[256 + lane] = __uint_as_float((unsigned int)v4);

        // ---- half-dot: 38 float4 h-reads (broadcast) x fresh weight regs ----
        const float* hbase = hw + cbase;
        float a0 = 0.f, a1 = 0.f, a2 = 0.f, a3 = 0.f;
        #pragma unroll
        for (int j = 0; j < 38; j++) {
            float4 h4 = *(const float4*)(hbase + 4*j);   // 2 addrs/wave -> broadcast
            a0 = fmaf(w4[j].x, h4.x, a0);
            a1 = fmaf(w4[j].y, h4.y, a1);
            a2 = fmaf(w4[j].z, h4.z, a2);
            a3 = fmaf(w4[j].w, h4.w, a3);
        }
        float sum = (a0 + a1) + (a2 + a3);
        sum += __shfl_xor(sum, 1);                 // combine halves
        const float acc = xw_t + sum;

        // ---- gate butterfly over tid bits 1..2 ----
        const float aa = acc;
        const float bb = __shfl_xor(acc, 2);
        const float cc = __shfl_xor(acc, 4);
        const float dd = __shfl_xor(bb, 4);
        const float vi = sel4(gate,     aa, bb, cc, dd);
        const float vf = sel4(gate ^ 1, aa, bb, cc, dd);
        const float vg = sel4(gate ^ 2, aa, bb, cc, dd);
        const float vo = sel4(gate ^ 3, aa, bb, cc, dd);

        c = sigm(vf) * c + sigm(vi) * tanh_fast(vg);
        const float h = sigm(vo) * tanh_fast(c);

        // ---- publish h_{t+1} + padded store (acks drain under next poll) ----
        if (storer) {
            const unsigned long long pv =
                ((unsigned long long)(unsigned int)(t + 1) << 32) |
                (unsigned long long)__float_as_uint(h);
            __hip_atomic_store(hb + (size_t)((t + 1) & 1) * 320 + d, pv,
                               __ATOMIC_RELAXED, __HIP_MEMORY_SCOPE_AGENT);
            padded[(size_t)m_t * D_ + pd] = h;
        }
    }
}

// ---------------- per-sentence attention + maxpool ---------------------------
__global__ __launch_bounds__(256) void attn_kernel(
    const int* __restrict__ lengths, const float* __restrict__ padded,
    float* __restrict__ out) {
    const int s = blockIdx.x;
    const int tid = threadIdx.x;
    const int Ls = lengths[s];
    const float* P = padded + (size_t)s * L_ * D_;
    __shared__ float sc[16][128];
    const float scale = 0.040824829046386304f;  // 1/sqrt(600)
    float vmax0 = -1e30f, vmax1 = -1e30f, vmax2 = -1e30f;

    const int nqt = (Ls + 15) / 16;
    for (int qt = 0; qt < nqt; qt++) {
        const int q0 = qt * 16;
        if (tid < 128) {
            float acc[16];
            #pragma unroll
            for (int i = 0; i < 16; i++) acc[i] = -1e30f;
            if (tid < Ls) {
                #pragma unroll
                for (int i = 0; i < 16; i++) acc[i] = 0.f;
                const float* pk = P + (size_t)tid * D_;
                for (int e4 = 0; e4 < 150; e4++) {
                    const float4 k4 = *(const float4*)(pk + 4*e4);
                    #pragma unroll
                    for (int i = 0; i < 16; i++) {
                        const float4 q4 = *(const float4*)(P + (size_t)(q0 + i) * D_ + 4*e4);
                        acc[i] = fmaf(k4.x, q4.x, acc[i]);
                        acc[i] = fmaf(k4.y, q4.y, acc[i]);
                        acc[i] = fmaf(k4.z, q4.z, acc[i]);
                        acc[i] = fmaf(k4.w, q4.w, acc[i]);
                    }
                }
                #pragma unroll
                for (int i = 0; i < 16; i++) acc[i] *= scale;
            }
            #pragma unroll
            for (int i = 0; i < 16; i++) sc[i][tid] = acc[i];
        }
        __syncthreads();

        {
            const int w = tid >> 6, l = tid & 63;
            #pragma unroll
            for (int ii = 0; ii < 4; ii++) {
                const int i = w * 4 + ii;
                float x0 = sc[i][l], x1 = sc[i][64 + l];
                float mx = fmaxf(x0, x1);
                #pragma unroll
                for (int off = 32; off; off >>= 1) mx = fmaxf(mx, __shfl_xor(mx, off));
                float e0 = expf(x0 - mx), e1 = expf(x1 - mx);
                float sm = e0 + e1;
                #pragma unroll
                for (int off = 32; off; off >>= 1) sm += __shfl_xor(sm, off);
                const float inv = 1.f / sm;
                sc[i][l] = e0 * inv;
                sc[i][64 + l] = e1 * inv;
            }
        }
        __syncthreads();

        #pragma unroll
        for (int j = 0; j < 3; j++) {
            const int dd = j * 256 + tid;
            if (dd < D_) {
                float ca[16];
                #pragma unroll
                for (int i = 0; i < 16; i++) ca[i] = 0.f;
                for (int k4 = 0; k4 < 32; k4++) {
                    const float p0 = P[(size_t)(4*k4 + 0) * D_ + dd];
                    const float p1 = P[(size_t)(4*k4 + 1) * D_ + dd];
                    const float p2 = P[(size_t)(4*k4 + 2) * D_ + dd];
                    const float p3 = P[(size_t)(4*k4 + 3) * D_ + dd];
                    #pragma unroll
                    for (int i = 0; i < 16; i++) {
                        const float4 pr = *(const float4*)(&sc[i][4*k4]);
                        ca[i] = fmaf(pr.x, p0, ca[i]);
                        ca[i] = fmaf(pr.y, p1, ca[i]);
                        ca[i] = fmaf(pr.z, p2, ca[i]);
                        ca[i] = fmaf(pr.w, p3, ca[i]);
                    }
                }
                float vm = (j == 0) ? vmax0 : (j == 1) ? vmax1 : vmax2;
                #pragma unroll
                for (int i = 0; i < 16; i++)
                    if (q0 + i < Ls) vm = fmaxf(vm, ca[i]);
                if (j == 0) vmax0 = vm; else if (j == 1) vmax1 = vm; else vmax2 = vm;
            }
        }
        __syncthreads();
    }
    if (tid < D_)        out[(size_t)s * D_ + tid] = vmax0;
    if (256 + tid < D_)  out[(size_t)s * D_ + 256 + tid] = vmax1;
    if (512 + tid < D_)  out[(size_t)s * D_ + 512 + tid] = vmax2;
}

// ---------------- launcher ----------------------------------------------------
extern "C" void kernel_launch(void* const* d_in, const int* in_sizes, int n_in,
                              void* d_out, int out_size, void* d_ws, size_t ws_size,
                              hipStream_t stream) {
    const int*   tokens  = (const int*)d_in[0];
    const int*   lengths = (const int*)d_in[1];
    const float* table   = (const float*)d_in[2];
    const float* Wih_f   = (const float*)d_in[3];
    const float* Whh_f   = (const float*)d_in[4];
    const float* bih_f   = (const float*)d_in[5];
    const float* bhh_f   = (const float*)d_in[6];
    const float* Wih_b   = (const float*)d_in[7];
    const float* Whh_b   = (const float*)d_in[8];
    const float* bih_b   = (const float*)d_in[9];
    const float* bhh_b   = (const float*)d_in[10];
    float* out = (float*)d_out;

    char* ws = (char*)d_ws;
    int* meta                 = (int*)(ws + 0);                       // 256 B
    int* map                  = (int*)(ws + 256);                     // 64 KB
    unsigned long long* hbuf  = (unsigned long long*)(ws + 256 + 65536);        // 10240 B
    float* xw                 = (float*)(ws + 256 + 65536 + 10240);   // 2*16384*1200 f32
    float* padded             = (float*)(ws + 256 + 65536 + 10240 + (size_t)2*NMAX*R_*4);

    prep_kernel<<<1, 256, 0, stream>>>(lengths, meta, map, hbuf);
    xw_kernel<<<dim3(NMAX/32, 10), 256, 0, stream>>>(tokens, table,
        Wih_f, bih_f, bhh_f, Wih_b, bih_b, bhh_b, meta, map, xw);
    scan_kernel<<<20, 256, 0, stream>>>(Whh_f, Whh_b, meta, map, hbuf, xw, padded);
    attn_kernel<<<S_, 256, 0, stream>>>(lengths, padded, out);
}

// Round 8
// 22362.909 us; speedup vs baseline: 1.5070x; 1.5070x over previous
//
#include <hip/hip_runtime.h>
#include <stdint.h>

#define S_ 128
#define L_ 128
#define E_ 300
#define H_ 300
#define NMAX (S_*L_)          // 16384
#define R_ 1200               // 4*H
#define D_ 600
#define XW_STRIDE ((size_t)NMAX*R_)

// ---------------- prep: prefix sums, token->(s,l) map, zero h buffers -------
__global__ void prep_kernel(const int* __restrict__ lengths, int* __restrict__ meta,
                            int* __restrict__ map, unsigned long long* __restrict__ hbuf) {
    __shared__ int offs[S_];
    int tid = threadIdx.x;
    if (tid == 0) {
        int acc = 0;
        for (int s = 0; s < S_; s++) { offs[s] = acc; acc += lengths[s]; }
        meta[0] = acc;   // N total
    }
    __syncthreads();
    for (int s = tid; s < S_; s += blockDim.x) {
        int o = offs[s], len = lengths[s];
        for (int l = 0; l < len; l++) map[o + l] = s * L_ + l;
    }
    // zero hbuf: [2 dirs][2 slots][320] u64 (tag 0 == valid h_0 = 0)
    for (int i = tid; i < 2*2*320; i += blockDim.x) hbuf[i] = 0ull;
}

// ---------------- xw = embeds @ Wih^T + (bih+bhh), both directions ----------
__global__ __launch_bounds__(256, 1) void xw_kernel(
    const int* __restrict__ tokens, const float* __restrict__ table,
    const float* __restrict__ Wih_f, const float* __restrict__ bih_f, const float* __restrict__ bhh_f,
    const float* __restrict__ Wih_b, const float* __restrict__ bih_b, const float* __restrict__ bhh_b,
    const int* __restrict__ meta, const int* __restrict__ map, float* __restrict__ xw) {
    const int N = meta[0];
    const int n0 = blockIdx.x * 32;
    if (n0 >= N) return;
    const int r = blockIdx.y * 256 + threadIdx.x;   // 0..2559
    const bool vr = (r < 2*R_);
    const int dir = (r >= R_) ? 1 : 0;
    const int rr = r - dir * R_;
    const float* W = dir ? Wih_b : Wih_f;
    float bias = 0.f;
    float4 w4[75];
    if (vr) {
        bias = dir ? (bih_b[rr] + bhh_b[rr]) : (bih_f[rr] + bhh_f[rr]);
        #pragma unroll
        for (int j = 0; j < 75; j++) w4[j] = *(const float4*)(W + (size_t)rr * E_ + 4*j);
    } else {
        #pragma unroll
        for (int j = 0; j < 75; j++) w4[j] = make_float4(0.f, 0.f, 0.f, 0.f);
    }
    float* xwd = xw + (size_t)dir * XW_STRIDE;
    const int iend = min(32, N - n0);
    for (int i = 0; i < iend; i++) {
        const int n = n0 + i;
        const int tok = tokens[map[n]];                  // uniform
        const float* arow = table + (size_t)tok * E_;
        float a0 = bias, a1 = 0.f, a2 = 0.f, a3 = 0.f;
        #pragma unroll
        for (int j = 0; j < 75; j++) {
            float4 a4 = *(const float4*)(arow + 4*j);    // uniform -> scalar path
            a0 = fmaf(w4[j].x, a4.x, a0);
            a1 = fmaf(w4[j].y, a4.y, a1);
            a2 = fmaf(w4[j].z, a4.z, a2);
            a3 = fmaf(w4[j].w, a4.w, a3);
        }
        if (vr) xwd[(size_t)n * R_ + rr] = (a0 + a1) + (a2 + a3);
    }
}

// ---------------- sequential BiLSTM scan -------------------------------------
__device__ __forceinline__ float sel4(int m, float a, float b, float c, float d) {
    float r = a;
    r = (m == 1) ? b : r;
    r = (m == 2) ? c : r;
    r = (m == 3) ? d : r;
    return r;
}
// fast activations (v_exp_f32 + v_rcp_f32); NaN-free at +/-inf
__device__ __forceinline__ float sigm(float x) {
    return __builtin_amdgcn_rcpf(1.f + __expf(-x));
}
__device__ __forceinline__ float tanh_fast(float x) {
    return 1.f - 2.f * __builtin_amdgcn_rcpf(1.f + __expf(2.f * x));
}

// grid: 20 blocks x 256 threads. block b: dir=b/10, blk=b%10 (30 h-dims).
// thread: pair=tid>>1 owns Whh row lr=pair (gate=pair&3, d=30*blk+(pair>>2));
// half=tid&1 owns half the 300-wide dot (half0: cols 0..151, half1: 152..299).
// WEIGHTS LIVE IN LDS (staged once at start; 120 rows x 300 f32 = 144 KB).
// The register allocator holds nothing loop-invariant -> no remat/spill
// pathology (R4-R7). Per-step weight reads are ds_read_b128 at ~256 B/cy.
// h exchanged via tagged u64 hbuf[dir][slot][dim] at AGENT scope (tag=step);
// 2 rotating slots are race-free because every block is producer AND consumer.
__global__ __launch_bounds__(256, 1) void scan_kernel(
    const float* __restrict__ Whh_f, const float* __restrict__ Whh_b,
    const int* __restrict__ meta, const int* __restrict__ map,
    unsigned long long* __restrict__ hbuf, const float* __restrict__ xw,
    float* __restrict__ padded) {
    const int N = meta[0];
    const int b = blockIdx.x;
    const int dir = b / 10;
    const int blk = b % 10;
    const int tid = threadIdx.x;
    const int wave = tid >> 6;
    const int lane = tid & 63;
    const int pair = tid >> 1;            // 0..127 (rows 120..127 invalid)
    const int half = tid & 1;
    const int gate = pair & 3;
    const int d = 30 * blk + (pair >> 2); // h dim this row-group computes
    const bool vd = (pair < 120);         // 30 dims x 4 gates

    __shared__ float w_lds[120][300];     // 144,000 B
    __shared__ float hl[4][300];          //   4,800 B  (total 148.8 KB)

    const float* Whh = dir ? Whh_b : Whh_f;
    // ---- stage this block's weight slice into LDS (once) ----
    for (int i = tid; i < 120 * 75; i += 256) {
        const int lr = i / 75;            // local row
        const int c4 = (i % 75) * 4;
        const int grow = (lr & 3) * H_ + blk * 30 + (lr >> 2);
        *(float4*)(&w_lds[lr][c4]) = *(const float4*)(Whh + (size_t)grow * H_ + c4);
    }
    __syncthreads();

    const int row = gate * H_ + (vd ? d : 0);      // xw row for this pair
    const int cbase = half ? 152 : 0;              // 152-col / 148-col halves
    const float* wrow = vd ? &w_lds[pair][cbase] : &w_lds[0][cbase];

    const float* xwd = xw + (size_t)dir * XW_STRIDE;
    unsigned long long* hb = hbuf + dir * 2 * 320;
    float* hw = hl[wave];

    float c = 0.f;
    const bool storer = (vd && gate == 0 && half == 0);
    const int pd = dir * H_ + d;

    for (int t = 0; t < N; t++) {
        const int n = dir ? (N - 1 - t) : t;
        // pre-poll: xw + map (2 regs; HBM latency hides under the poll)
        const float xw_t = vd ? xwd[(size_t)n * R_ + row] : 0.f;
        const int   m_t  = map[n];

        // ---- poll h_t (tag == t) ----
        const unsigned long long* hp = hb + (size_t)(t & 1) * 320;
        const unsigned int want = (unsigned int)t;
        unsigned long long v0, v1, v2, v3, v4;
        for (;;) {
            v0 = __hip_atomic_load(hp + lane,        __ATOMIC_RELAXED, __HIP_MEMORY_SCOPE_AGENT);
            v1 = __hip_atomic_load(hp + 64  + lane,  __ATOMIC_RELAXED, __HIP_MEMORY_SCOPE_AGENT);
            v2 = __hip_atomic_load(hp + 128 + lane,  __ATOMIC_RELAXED, __HIP_MEMORY_SCOPE_AGENT);
            v3 = __hip_atomic_load(hp + 192 + lane,  __ATOMIC_RELAXED, __HIP_MEMORY_SCOPE_AGENT);
            v4 = (lane < 44) ? __hip_atomic_load(hp + 256 + lane, __ATOMIC_RELAXED, __HIP_MEMORY_SCOPE_AGENT)
                             : ((unsigned long long)want << 32);
            bool ok = ((unsigned int)(v0 >> 32) == want) &&
                      ((unsigned int)(v1 >> 32) == want) &&
                      ((unsigned int)(v2 >> 32) == want) &&
                      ((unsigned int)(v3 >> 32) == want) &&
                      ((unsigned int)(v4 >> 32) == want);
            if (ok) break;
        }
        // stage h into this wave's LDS copy
        hw[lane]        = __uint_as_float((unsigned int)v0);
        hw[64  + lane]  = __uint_as_float((unsigned int)v1);
        hw[128 + lane]  = __uint_as_float((unsigned int)v2);
        hw[192 + lane]  = __uint_as_float((unsigned int)v3);
        if (lane < 44) hw[256 + lane] = __uint_as_float((unsigned int)v4);

        // ---- half-dot: weights AND h from LDS (37 common f4 + 1 for half0) --
        const float* hbase = hw + cbase;
        float a0 = 0.f, a1 = 0.f, a2 = 0.f, a3 = 0.f;
        #pragma unroll
        for (int j = 0; j < 37; j++) {
            const float4 wj = *(const float4*)(wrow + 4*j);
            const float4 h4 = *(const float4*)(hbase + 4*j);
            a0 = fmaf(wj.x, h4.x, a0);
            a1 = fmaf(wj.y, h4.y, a1);
            a2 = fmaf(wj.z, h4.z, a2);
            a3 = fmaf(wj.w, h4.w, a3);
        }
        if (half == 0) {   // half0 covers 152 cols (one extra float4)
            const float4 wj = *(const float4*)(wrow + 148);
            const float4 h4 = *(const float4*)(hbase + 148);
            a0 = fmaf(wj.x, h4.x, a0);
            a1 = fmaf(wj.y, h4.y, a1);
            a2 = fmaf(wj.z, h4.z, a2);
            a3 = fmaf(wj.w, h4.w, a3);
        }
        float sum = (a0 + a1) + (a2 + a3);
        sum += __shfl_xor(sum, 1);                 // combine halves
        const float acc = xw_t + sum;

        // ---- gate butterfly over tid bits 1..2 ----
        const float aa = acc;
        const float bb = __shfl_xor(acc, 2);
        const float cc = __shfl_xor(acc, 4);
        const float dd = __shfl_xor(bb, 4);
        const float vi = sel4(gate,     aa, bb, cc, dd);
        const float vf = sel4(gate ^ 1, aa, bb, cc, dd);
        const float vg = sel4(gate ^ 2, aa, bb, cc, dd);
        const float vo = sel4(gate ^ 3, aa, bb, cc, dd);

        c = sigm(vf) * c + sigm(vi) * tanh_fast(vg);
        const float h = sigm(vo) * tanh_fast(c);

        // ---- publish h_{t+1}; padded store rides behind it ----
        if (storer) {
            const unsigned long long pv =
                ((unsigned long long)(unsigned int)(t + 1) << 32) |
                (unsigned long long)__float_as_uint(h);
            __hip_atomic_store(hb + (size_t)((t + 1) & 1) * 320 + d, pv,
                               __ATOMIC_RELAXED, __HIP_MEMORY_SCOPE_AGENT);
            padded[(size_t)m_t * D_ + pd] = h;
        }
    }
}

// ---------------- per-sentence attention + maxpool ---------------------------
__global__ __launch_bounds__(256) void attn_kernel(
    const int* __restrict__ lengths, const float* __restrict__ padded,
    float* __restrict__ out) {
    const int s = blockIdx.x;
    const int tid = threadIdx.x;
    const int Ls = lengths[s];
    const float* P = padded + (size_t)s * L_ * D_;
    __shared__ float sc[16][128];
    const float scale = 0.040824829046386304f;  // 1/sqrt(600)
    float vmax0 = -1e30f, vmax1 = -1e30f, vmax2 = -1e30f;

    const int nqt = (Ls + 15) / 16;
    for (int qt = 0; qt < nqt; qt++) {
        const int q0 = qt * 16;
        if (tid < 128) {
            float acc[16];
            #pragma unroll
            for (int i = 0; i < 16; i++) acc[i] = -1e30f;
            if (tid < Ls) {
                #pragma unroll
                for (int i = 0; i < 16; i++) acc[i] = 0.f;
                const float* pk = P + (size_t)tid * D_;
                for (int e4 = 0; e4 < 150; e4++) {
                    const float4 k4 = *(const float4*)(pk + 4*e4);
                    #pragma unroll
                    for (int i = 0; i < 16; i++) {
                        const float4 q4 = *(const float4*)(P + (size_t)(q0 + i) * D_ + 4*e4);
                        acc[i] = fmaf(k4.x, q4.x, acc[i]);
                        acc[i] = fmaf(k4.y, q4.y, acc[i]);
                        acc[i] = fmaf(k4.z, q4.z, acc[i]);
                        acc[i] = fmaf(k4.w, q4.w, acc[i]);
                    }
                }
                #pragma unroll
                for (int i = 0; i < 16; i++) acc[i] *= scale;
            }
            #pragma unroll
            for (int i = 0; i < 16; i++) sc[i][tid] = acc[i];
        }
        __syncthreads();

        {
            const int w = tid >> 6, l = tid & 63;
            #pragma unroll
            for (int ii = 0; ii < 4; ii++) {
                const int i = w * 4 + ii;
                float x0 = sc[i][l], x1 = sc[i][64 + l];
                float mx = fmaxf(x0, x1);
                #pragma unroll
                for (int off = 32; off; off >>= 1) mx = fmaxf(mx, __shfl_xor(mx, off));
                float e0 = expf(x0 - mx), e1 = expf(x1 - mx);
                float sm = e0 + e1;
                #pragma unroll
                for (int off = 32; off; off >>= 1) sm += __shfl_xor(sm, off);
                const float inv = 1.f / sm;
                sc[i][l] = e0 * inv;
                sc[i][64 + l] = e1 * inv;
            }
        }
        __syncthreads();

        #pragma unroll
        for (int j = 0; j < 3; j++) {
            const int dd = j * 256 + tid;
            if (dd < D_) {
                float ca[16];
                #pragma unroll
                for (int i = 0; i < 16; i++) ca[i] = 0.f;
                for (int k4 = 0; k4 < 32; k4++) {
                    const float p0 = P[(size_t)(4*k4 + 0) * D_ + dd];
                    const float p1 = P[(size_t)(4*k4 + 1) * D_ + dd];
                    const float p2 = P[(size_t)(4*k4 + 2) * D_ + dd];
                    const float p3 = P[(size_t)(4*k4 + 3) * D_ + dd];
                    #pragma unroll
                    for (int i = 0; i < 16; i++) {
                        const float4 pr = *(const float4*)(&sc[i][4*k4]);
                        ca[i] = fmaf(pr.x, p0, ca[i]);
                        ca[i] = fmaf(pr.y, p1, ca[i]);
                        ca[i] = fmaf(pr.z, p2, ca[i]);
                        ca[i] = fmaf(pr.w, p3, ca[i]);
                    }
                }
                float vm = (j == 0) ? vmax0 : (j == 1) ? vmax1 : vmax2;
                #pragma unroll
                for (int i = 0; i < 16; i++)
                    if (q0 + i < Ls) vm = fmaxf(vm, ca[i]);
                if (j == 0) vmax0 = vm; else if (j == 1) vmax1 = vm; else vmax2 = vm;
            }
        }
        __syncthreads();
    }
    if (tid < D_)        out[(size_t)s * D_ + tid] = vmax0;
    if (256 + tid < D_)  out[(size_t)s * D_ + 256 + tid] = vmax1;
    if (512 + tid < D_)  out[(size_t)s * D_ + 512 + tid] = vmax2;
}

// ---------------- launcher ----------------------------------------------------
extern "C" void kernel_launch(void* const* d_in, const int* in_sizes, int n_in,
                              void* d_out, int out_size, void* d_ws, size_t ws_size,
                              hipStream_t stream) {
    const int*   tokens  = (const int*)d_in[0];
    const int*   lengths = (const int*)d_in[1];
    const float* table   = (const float*)d_in[2];
    const float* Wih_f   = (const float*)d_in[3];
    const float* Whh_f   = (const float*)d_in[4];
    const float* bih_f   = (const float*)d_in[5];
    const float* bhh_f   = (const float*)d_in[6];
    const float* Wih_b   = (const float*)d_in[7];
    const float* Whh_b   = (const float*)d_in[8];
    const float* bih_b   = (const float*)d_in[9];
    const float* bhh_b   = (const float*)d_in[10];
    float* out = (float*)d_out;

    char* ws = (char*)d_ws;
    int* meta                 = (int*)(ws + 0);                       // 256 B
    int* map                  = (int*)(ws + 256);                     // 64 KB
    unsigned long long* hbuf  = (unsigned long long*)(ws + 256 + 65536);        // 10240 B
    float* xw                 = (float*)(ws + 256 + 65536 + 10240);   // 2*16384*1200 f32
    float* padded             = (float*)(ws + 256 + 65536 + 10240 + (size_t)2*NMAX*R_*4);

    prep_kernel<<<1, 256, 0, stream>>>(lengths, meta, map, hbuf);
    xw_kernel<<<dim3(NMAX/32, 10), 256, 0, stream>>>(tokens, table,
        Wih_f, bih_f, bhh_f, Wih_b, bih_b, bhh_b, meta, map, xw);
    scan_kernel<<<20, 256, 0, stream>>>(Whh_f, Whh_b, meta, map, hbuf, xw, padded);
    attn_kernel<<<S_, 256, 0, stream>>>(lengths, padded, out);
}